// Round 9
// baseline (135.304 us; speedup 1.0000x reference)
//
#include <hip/hip_runtime.h>

#define EPSF 1e-5f

typedef _Float16 half8 __attribute__((ext_vector_type(8)));
typedef float f32x4 __attribute__((ext_vector_type(4)));

__device__ __forceinline__ float clamp01(float x){ return fminf(fmaxf(x, 0.f), 1.f); }

// ---------------- prep: effective 6x6 pooled-conv weights + bn folding ----------------
// Identity: 2x2-pool(conv5x5) = stride-2 conv6x6 with W'[u][v] = sum_{r,c in {0,1}} w[u-r][v-c].
// Column pairing (s1/s2 tables): col c<16 -> oc=2c ; c>=16 -> oc=2(c-16)+1.
// w1e[col32][k192]   k = u*32 + v*4 + ic   (v<6, ic<3 used; rest zero)
// w2e[tap36][col32][ic32]   tap = u*6+v
// w3e[tap36][oc64][ic32]    (natural oc order)
// w4h[oc16][k1024]          k = pos*64+ic
// bnc: [0,32) s1scale(1/4 folded) [32,64) s1shift [64,96) s2scale [96,128) s2shift
//      [128,192) s3scale [192,256) s3shift [256,266) s4scale [266,276) s4shift
__global__ __launch_bounds__(256) void k_prep(
    const float* __restrict__ w1, const float* __restrict__ w2,
    const float* __restrict__ w3, const float* __restrict__ w4,
    const float* __restrict__ g1, const float* __restrict__ b1, const float* __restrict__ m1, const float* __restrict__ v1,
    const float* __restrict__ g2, const float* __restrict__ b2, const float* __restrict__ m2, const float* __restrict__ v2,
    const float* __restrict__ g3, const float* __restrict__ b3, const float* __restrict__ m3, const float* __restrict__ v3,
    const float* __restrict__ g4, const float* __restrict__ b4, const float* __restrict__ m4, const float* __restrict__ v4,
    _Float16* __restrict__ w1e, _Float16* __restrict__ w2e, _Float16* __restrict__ w3e,
    _Float16* __restrict__ w4h, float* __restrict__ bnc)
{
  const int t = blockIdx.x*256 + threadIdx.x;   // grid 128 -> 32768 threads
  if (t < 6144) {                               // w1e: 32 cols x 192 k
    int c = t / 192, k = t - c*192;
    int oc = (c < 16) ? 2*c : 2*(c-16)+1;
    int u = k >> 5, rem = k & 31, v = rem >> 2, ic = rem & 3;
    float val = 0.f;
    if (v < 6 && ic < 3) {
      #pragma unroll
      for (int r = 0; r < 2; ++r)
        #pragma unroll
        for (int cc = 0; cc < 2; ++cc) {
          int uu = u - r, vv = v - cc;
          if ((unsigned)uu < 5u && (unsigned)vv < 5u)
            val += w1[(oc*3+ic)*25 + uu*5 + vv];
        }
    }
    w1e[t] = (_Float16)val;
  }
  for (int i = t; i < 36864; i += 32768) {      // w2e: 36 x 32col x 32ic
    int tap = i >> 10, r2 = i & 1023, c = r2 >> 5, ic = r2 & 31;
    int oc = (c < 16) ? 2*c : 2*(c-16)+1;
    int u = tap / 6, v = tap - u*6;
    float val = 0.f;
    #pragma unroll
    for (int r = 0; r < 2; ++r)
      #pragma unroll
      for (int cc = 0; cc < 2; ++cc) {
        int uu = u - r, vv = v - cc;
        if ((unsigned)uu < 5u && (unsigned)vv < 5u)
          val += w2[(oc*32+ic)*25 + uu*5 + vv];
      }
    w2e[i] = (_Float16)val;
  }
  for (int i = t; i < 73728; i += 32768) {      // w3e: 36 x 64oc x 32ic
    int tap = i >> 11, r2 = i & 2047, oc = r2 >> 5, ic = r2 & 31;
    int u = tap / 6, v = tap - u*6;
    float val = 0.f;
    #pragma unroll
    for (int r = 0; r < 2; ++r)
      #pragma unroll
      for (int cc = 0; cc < 2; ++cc) {
        int uu = u - r, vv = v - cc;
        if ((unsigned)uu < 5u && (unsigned)vv < 5u)
          val += w3[(oc*32+ic)*25 + uu*5 + vv];
      }
    w3e[i] = (_Float16)val;
  }
  for (int i = t; i < 16384; i += 32768) {
    int oc = i >> 10, k = i & 1023, pos = k >> 6, ic = k & 63;
    float val = (oc < 10) ? w4[(oc*64+ic)*16 + pos] : 0.f;
    w4h[i] = (_Float16)val;
  }
  if (t < 32) {
    float inv = g1[t] / sqrtf(v1[t] + EPSF);
    bnc[t] = 0.25f*inv; bnc[32+t] = b1[t] - m1[t]*inv;
    float i2 = g2[t] / sqrtf(v2[t] + EPSF);
    bnc[64+t] = 0.25f*i2; bnc[96+t] = b2[t] - m2[t]*i2;
  }
  if (t < 64) {
    float i3 = g3[t] / sqrtf(v3[t] + EPSF);
    bnc[128+t] = 0.25f*i3; bnc[192+t] = b3[t] - m3[t]*i3;
  }
  if (t < 10) {
    float i4 = g4[t] / sqrtf(v4[t] + EPSF);
    bnc[256+t] = i4; bnc[266+t] = b4[t] - m4[t]*i4;
  }
}

// ---------------- fused: all 4 stages, one image per block, 512 thr / 8 waves ------
// No box filters anywhere: 6x6 effective kernels read raw padded activations.
// LDS overlays (byte offsets, 32000 B):
//   ph0-1: Pimg f16[36][40][4] @0 (11520)   padded raw image, channel-last
//   ph2-3: P2  f16[20][20][40] @0 (32000)   padded s1 output (over dead Pimg)
//   ph4-5: P3  f16[12][12][40] @0 (11520)   Ip3 f16[16][64] @11520 (2048)
//   ph6:   S4P f32[160] @13568 (640)
__global__ __launch_bounds__(512, 6) void k_fused(
    const float* __restrict__ x,
    const _Float16* __restrict__ w1e, const _Float16* __restrict__ w2e,
    const _Float16* __restrict__ w3e, const _Float16* __restrict__ w4h,
    const float* __restrict__ bnc, float* __restrict__ out)
{
  __shared__ __align__(16) char arena[32000];
  _Float16* Pimg = (_Float16*)arena;           // [36 rows][40 cols][4 ic]
  _Float16* P2   = (_Float16*)arena;           // [20][20][40]
  _Float16* P3   = (_Float16*)arena;           // [12][12][40]
  _Float16* Ip3  = (_Float16*)(arena + 11520); // [16][64]
  float*    S4P  = (float*)(arena + 13568);    // [160]

  const int img = blockIdx.x;
  const int tid = threadIdx.x;
  const int w   = __builtin_amdgcn_readfirstlane(tid >> 6);  // wave 0..7
  const int l   = tid & 63;
  const int row = l & 15;          // A-row / B-col lane index
  const int kg  = l >> 4;          // k-group (8 halfs)
  const int mtb = w & 3;
  const int ntb = w >> 2;

  // ---------- ph0a: zero Pimg (pads + overhang) ----------
  for (int i = tid; i < 720; i += 512)
    ((float4*)arena)[i] = make_float4(0.f,0.f,0.f,0.f);
  __syncthreads();                               // b0

  // ---------- ph0b: interior fill, f32->f16 channel-last transpose ----------
  {
    const float* xin = x + img*3072;
    for (int i = tid; i < 768; i += 512) {       // [3 ic][32 y][8 xq]
      int ic = i >> 8, rem = i & 255;
      int y = rem >> 3, xq = rem & 7;
      float4 v4 = *(const float4*)(xin + ic*1024 + y*32 + xq*4);
      _Float16* dst = Pimg + (y+2)*160 + (xq*4 + 2)*4 + ic;
      dst[0]  = (_Float16)v4.x; dst[4]  = (_Float16)v4.y;
      dst[8]  = (_Float16)v4.z; dst[12] = (_Float16)v4.w;
    }
  }
  __syncthreads();                               // b1: Pimg ready

  // ---------- ph1: s1 MFMA  wave = ntb oc-tile, 4 pooled rows; K=192 (6 chunks) ----
  f32x4 acc1[4];
  {
    half8 B1[6];
    #pragma unroll
    for (int u = 0; u < 6; ++u)
      B1[u] = *(const half8*)(w1e + (ntb*16 + row)*192 + u*32 + kg*8);
    #pragma unroll
    for (int t2 = 0; t2 < 4; ++t2) acc1[t2] = (f32x4){0,0,0,0};
    const int xoff = 8*(row + kg);
    #pragma unroll
    for (int t2 = 0; t2 < 4; ++t2) {
      const int py = mtb*4 + t2;
      #pragma unroll
      for (int u = 0; u < 6; ++u) {
        half8 av = *(const half8*)(Pimg + (2*py + u)*160 + xoff);
        acc1[t2] = __builtin_amdgcn_mfma_f32_16x16x32_f16(av, B1[u], acc1[t2], 0, 0, 0);
      }
    }
  }
  __syncthreads();                               // b2: Pimg dead

  // ---------- ph2: zero P2 border + write s1 output (oc = 2*row + ntb) ----------
  for (int j = tid; j < 1600; j += 512) {
    int u = j & 3, pos = j >> 2;
    int a = pos/20, c = pos - a*20;
    bool interior = ((unsigned)(a-2) < 16u) & ((unsigned)(c-2) < 16u);
    if (!interior) *(half8*)(P2 + pos*40 + u*8) = (half8)(_Float16)0.f;
  }
  {
    const int oc = 2*row + ntb;
    const float sA = bnc[oc], hA = bnc[32 + oc];
    #pragma unroll
    for (int t2 = 0; t2 < 4; ++t2) {
      const int py = mtb*4 + t2;
      #pragma unroll
      for (int r = 0; r < 4; ++r) {
        int px = kg*4 + r;
        P2[((py+2)*20 + px+2)*40 + oc] = (_Float16)clamp01(fmaf(acc1[t2][r], sA, hA));
      }
    }
  }
  __syncthreads();                               // b3: P2 complete

  // ---------- ph3: s2 MFMA, 36 taps, depth-4 weight prefetch, zero VALU ----------
  f32x4 a2 = {0,0,0,0};
  {
    const int pixel = mtb*16 + row;
    const int py = pixel >> 3, px = pixel & 7;
    const _Float16* base = P2 + (2*py)*800 + (2*px)*40 + kg*8;
    const _Float16* wb = w2e + (ntb*16 + row)*32 + kg*8;
    half8 wreg[4];
    #pragma unroll
    for (int q = 0; q < 4; ++q) wreg[q] = *(const half8*)(wb + q*1024);
    #pragma unroll
    for (int u = 0; u < 6; ++u)
      #pragma unroll
      for (int v = 0; v < 6; ++v) {
        const int tap = u*6 + v;
        const int tn = (tap < 32) ? tap + 4 : tap;   // prefetch 4 ahead
        half8 nw = *(const half8*)(wb + tn*1024);
        half8 av = *(const half8*)(base + u*800 + v*40);
        a2 = __builtin_amdgcn_mfma_f32_16x16x32_f16(av, wreg[tap & 3], a2, 0, 0, 0);
        wreg[tap & 3] = nw;
      }
  }
  __syncthreads();                               // b4: P2 reads done

  // ---------- ph4: zero P3 border + write s2 output (oc = 2*row + ntb) ----------
  for (int j = tid; j < 576; j += 512) {
    int u = j & 3, pos = j >> 2;
    int a = pos/12, c = pos - a*12;
    bool interior = ((unsigned)(a-2) < 8u) & ((unsigned)(c-2) < 8u);
    if (!interior) *(half8*)(P3 + pos*40 + u*8) = (half8)(_Float16)0.f;
  }
  {
    const int oc = 2*row + ntb;
    const float sA = bnc[64 + oc], hA = bnc[96 + oc];
    #pragma unroll
    for (int r = 0; r < 4; ++r) {
      int p2 = mtb*16 + kg*4 + r;
      int py2 = p2 >> 3, px2 = p2 & 7;
      P3[((py2+2)*12 + px2+2)*40 + oc] = (_Float16)clamp01(fmaf(a2[r], sA, hA));
    }
  }
  __syncthreads();                               // b5: P3 complete

  // ---------- ph5: s3 MFMA (waves 0-3), 36 taps, depth-4 prefetch ----------
  if (w < 4) {
    const int py = row >> 2, px = row & 3;
    const _Float16* base = P3 + (2*py)*480 + (2*px)*40 + kg*8;
    const _Float16* wb = w3e + (w*16 + row)*32 + kg*8;
    half8 wreg[4];
    #pragma unroll
    for (int q = 0; q < 4; ++q) wreg[q] = *(const half8*)(wb + q*2048);
    f32x4 a3 = {0,0,0,0};
    #pragma unroll
    for (int u = 0; u < 6; ++u)
      #pragma unroll
      for (int v = 0; v < 6; ++v) {
        const int tap = u*6 + v;
        const int tn = (tap < 32) ? tap + 4 : tap;
        half8 nw = *(const half8*)(wb + tn*2048);
        half8 av = *(const half8*)(base + u*480 + v*40);
        a3 = __builtin_amdgcn_mfma_f32_16x16x32_f16(av, wreg[tap & 3], a3, 0, 0, 0);
        wreg[tap & 3] = nw;
      }
    const int oc = w*16 + row;
    const float s3 = bnc[128 + oc], h3 = bnc[192 + oc];
    #pragma unroll
    for (int r = 0; r < 4; ++r)
      Ip3[(kg*4 + r)*64 + oc] = (_Float16)clamp01(fmaf(a3[r], s3, h3));
  }
  __syncthreads();                               // b6: Ip3 complete

  // ---------- ph6: fc 64x4x4 -> 10  + bn1d (VALU, f32 accum) ----------
  if (tid < 160) {
    const int oc = tid >> 4, pix = tid & 15;
    const _Float16* A = Ip3 + pix*64;
    const _Float16* W = w4h + oc*1024 + pix*64;
    float a = 0.f;
    #pragma unroll
    for (int q = 0; q < 8; ++q) {
      half8 xa = *(const half8*)(A + q*8);
      half8 wv = *(const half8*)(W + q*8);
      #pragma unroll
      for (int j = 0; j < 8; ++j)
        a = fmaf((float)xa[j], (float)wv[j], a);
    }
    S4P[tid] = a;
  }
  __syncthreads();                               // b7
  if (tid < 10) {
    float s = 0.f;
    #pragma unroll
    for (int i = 0; i < 16; ++i) s += S4P[tid*16 + i];
    out[img*10 + tid] = fmaf(s, bnc[256 + tid], bnc[266 + tid]);
  }
}

extern "C" void kernel_launch(void* const* d_in, const int* in_sizes, int n_in,
                              void* d_out, int out_size, void* d_ws, size_t ws_size,
                              hipStream_t stream)
{
  const float* x  = (const float*)d_in[0];
  const float* w1 = (const float*)d_in[1];
  const float* w2 = (const float*)d_in[2];
  const float* w3 = (const float*)d_in[3];
  const float* w4 = (const float*)d_in[4];
  const float *g1=(const float*)d_in[5],  *b1=(const float*)d_in[6],
              *m1=(const float*)d_in[7],  *v1=(const float*)d_in[8];
  const float *g2=(const float*)d_in[9],  *b2=(const float*)d_in[10],
              *m2=(const float*)d_in[11], *v2=(const float*)d_in[12];
  const float *g3=(const float*)d_in[13], *b3=(const float*)d_in[14],
              *m3=(const float*)d_in[15], *v3=(const float*)d_in[16];
  const float *g4=(const float*)d_in[17], *b4=(const float*)d_in[18],
              *m4=(const float*)d_in[19], *v4=(const float*)d_in[20];
  float* out = (float*)d_out;

  char* ws = (char*)d_ws;
  _Float16* w1e = (_Float16*)(ws);             //  12,288 B
  _Float16* w2e = (_Float16*)(ws + 12288);     //  73,728 B
  _Float16* w3e = (_Float16*)(ws + 86016);     // 147,456 B
  _Float16* w4h = (_Float16*)(ws + 233472);    //  32,768 B
  float*    bnc = (float*)   (ws + 266240);    //   1,152 B

  k_prep<<<dim3(128), dim3(256), 0, stream>>>(w1, w2, w3, w4,
      g1,b1,m1,v1, g2,b2,m2,v2, g3,b3,m3,v3, g4,b4,m4,v4,
      w1e, w2e, w3e, w4h, bnc);
  k_fused<<<dim3(1024), dim3(512), 0, stream>>>(x, w1e, w2e, w3e, w4h, bnc, out);
}

// Round 11
// 126.296 us; speedup vs baseline: 1.0713x; 1.0713x over previous
//
#include <hip/hip_runtime.h>

#define EPSF 1e-5f

typedef _Float16 half8 __attribute__((ext_vector_type(8)));
typedef float f32x4 __attribute__((ext_vector_type(4)));

__device__ __forceinline__ float clamp01(float x){ return fminf(fmaxf(x, 0.f), 1.f); }

// ---------------- prep: effective 6x6 pooled-conv weights + bn folding ----------------
// Identity: 2x2-pool(conv5x5) = stride-2 conv6x6 with W'[u][v] = sum_{r,c in {0,1}} w[u-r][v-c].
// Column pairing (s1/s2 tables): col c<16 -> oc=2c ; c>=16 -> oc=2(c-16)+1.
// w1e[col32][k192]   k = u*32 + v*4 + ic   (v<6, ic<3 used; rest zero)
// w2e[tap36][col32][ic32]   tap = u*6+v
// w3e[tap36][oc64][ic32]    (natural oc order)
// w4h[oc16][k1024]          k = pos*64+ic
// bnc: [0,32) s1scale(1/4 folded) [32,64) s1shift [64,96) s2scale [96,128) s2shift
//      [128,192) s3scale [192,256) s3shift [256,266) s4scale [266,276) s4shift
__global__ __launch_bounds__(256) void k_prep(
    const float* __restrict__ w1, const float* __restrict__ w2,
    const float* __restrict__ w3, const float* __restrict__ w4,
    const float* __restrict__ g1, const float* __restrict__ b1, const float* __restrict__ m1, const float* __restrict__ v1,
    const float* __restrict__ g2, const float* __restrict__ b2, const float* __restrict__ m2, const float* __restrict__ v2,
    const float* __restrict__ g3, const float* __restrict__ b3, const float* __restrict__ m3, const float* __restrict__ v3,
    const float* __restrict__ g4, const float* __restrict__ b4, const float* __restrict__ m4, const float* __restrict__ v4,
    _Float16* __restrict__ w1e, _Float16* __restrict__ w2e, _Float16* __restrict__ w3e,
    _Float16* __restrict__ w4h, float* __restrict__ bnc)
{
  const int t = blockIdx.x*256 + threadIdx.x;   // grid 128 -> 32768 threads
  if (t < 6144) {                               // w1e: 32 cols x 192 k
    int c = t / 192, k = t - c*192;
    int oc = (c < 16) ? 2*c : 2*(c-16)+1;
    int u = k >> 5, rem = k & 31, v = rem >> 2, ic = rem & 3;
    float val = 0.f;
    if (v < 6 && ic < 3) {
      #pragma unroll
      for (int r = 0; r < 2; ++r)
        #pragma unroll
        for (int cc = 0; cc < 2; ++cc) {
          int uu = u - r, vv = v - cc;
          if ((unsigned)uu < 5u && (unsigned)vv < 5u)
            val += w1[(oc*3+ic)*25 + uu*5 + vv];
        }
    }
    w1e[t] = (_Float16)val;
  }
  for (int i = t; i < 36864; i += 32768) {      // w2e: 36 x 32col x 32ic
    int tap = i >> 10, r2 = i & 1023, c = r2 >> 5, ic = r2 & 31;
    int oc = (c < 16) ? 2*c : 2*(c-16)+1;
    int u = tap / 6, v = tap - u*6;
    float val = 0.f;
    #pragma unroll
    for (int r = 0; r < 2; ++r)
      #pragma unroll
      for (int cc = 0; cc < 2; ++cc) {
        int uu = u - r, vv = v - cc;
        if ((unsigned)uu < 5u && (unsigned)vv < 5u)
          val += w2[(oc*32+ic)*25 + uu*5 + vv];
      }
    w2e[i] = (_Float16)val;
  }
  for (int i = t; i < 73728; i += 32768) {      // w3e: 36 x 64oc x 32ic
    int tap = i >> 11, r2 = i & 2047, oc = r2 >> 5, ic = r2 & 31;
    int u = tap / 6, v = tap - u*6;
    float val = 0.f;
    #pragma unroll
    for (int r = 0; r < 2; ++r)
      #pragma unroll
      for (int cc = 0; cc < 2; ++cc) {
        int uu = u - r, vv = v - cc;
        if ((unsigned)uu < 5u && (unsigned)vv < 5u)
          val += w3[(oc*32+ic)*25 + uu*5 + vv];
      }
    w3e[i] = (_Float16)val;
  }
  for (int i = t; i < 16384; i += 32768) {
    int oc = i >> 10, k = i & 1023, pos = k >> 6, ic = k & 63;
    float val = (oc < 10) ? w4[(oc*64+ic)*16 + pos] : 0.f;
    w4h[i] = (_Float16)val;
  }
  if (t < 32) {
    float inv = g1[t] / sqrtf(v1[t] + EPSF);
    bnc[t] = 0.25f*inv; bnc[32+t] = b1[t] - m1[t]*inv;
    float i2 = g2[t] / sqrtf(v2[t] + EPSF);
    bnc[64+t] = 0.25f*i2; bnc[96+t] = b2[t] - m2[t]*i2;
  }
  if (t < 64) {
    float i3 = g3[t] / sqrtf(v3[t] + EPSF);
    bnc[128+t] = 0.25f*i3; bnc[192+t] = b3[t] - m3[t]*i3;
  }
  if (t < 10) {
    float i4 = g4[t] / sqrtf(v4[t] + EPSF);
    bnc[256+t] = i4; bnc[266+t] = b4[t] - m4[t]*i4;
  }
}

// ---------------- fused: all 4 stages, TWO images per block, 512 thr / 8 waves ------
// Per tap: ONE weight load feeds TWO MFMAs (img0, img1) -> ILP 2, half weight traffic.
// LDS overlays (byte offsets, 64000 B):
//   ph0-1: Pimg f16[2][36][40][4] @0 (23040)
//   ph2-3: P2   f16[2][20][20][40] @0 (64000)
//   ph4-5: P3   f16[2][12][12][40] @0 (23040)   Ip3 f16[2][16][64] @23040 (4096)
//   ph6:   S4P  f32[2][160] @27136 (1280)
__global__ __launch_bounds__(512, 4) void k_fused(
    const float* __restrict__ x,
    const _Float16* __restrict__ w1e, const _Float16* __restrict__ w2e,
    const _Float16* __restrict__ w3e, const _Float16* __restrict__ w4h,
    const float* __restrict__ bnc, float* __restrict__ out)
{
  __shared__ __align__(16) char arena[64000];
  _Float16* Pimg = (_Float16*)arena;           // [2][36][40][4]  (img stride 5760 halfs)
  _Float16* P2   = (_Float16*)arena;           // [2][20][20][40] (img stride 16000 halfs)
  _Float16* P3   = (_Float16*)arena;           // [2][12][12][40] (img stride 5760 halfs)
  _Float16* Ip3  = (_Float16*)(arena + 23040); // [2][16][64]
  float*    S4P  = (float*)(arena + 27136);    // [2][160]

  const int i0  = blockIdx.x * 2;
  const int tid = threadIdx.x;
  const int w   = __builtin_amdgcn_readfirstlane(tid >> 6);  // wave 0..7
  const int l   = tid & 63;
  const int row = l & 15;          // A-row / B-col lane index
  const int kg  = l >> 4;          // k-group (8 halfs)
  const int mtb = w & 3;
  const int ntb = w >> 2;

  // ---------- ph0a: zero Pimg (both imgs, pads + overhang) ----------
  for (int i = tid; i < 1440; i += 512)
    ((float4*)arena)[i] = make_float4(0.f,0.f,0.f,0.f);
  __syncthreads();                               // b0

  // ---------- ph0b: interior fill, f32->f16 channel-last transpose, 2 imgs ----------
  // 1536 items = [2 im][3 ic][32 y][8 xq]; im = i/768 (NOT i>>9 -- R10 OOB bug)
  for (int i = tid; i < 1536; i += 512) {
    int im = i / 768, rem2 = i - im*768;
    int ic = rem2 >> 8, rem = rem2 & 255;
    int y = rem >> 3, xq = rem & 7;
    float4 v4 = *(const float4*)(x + (i0+im)*3072 + ic*1024 + y*32 + xq*4);
    _Float16* dst = Pimg + im*5760 + (y+2)*160 + (xq*4 + 2)*4 + ic;
    dst[0]  = (_Float16)v4.x; dst[4]  = (_Float16)v4.y;
    dst[8]  = (_Float16)v4.z; dst[12] = (_Float16)v4.w;
  }
  __syncthreads();                               // b1: Pimg ready

  // ---------- ph1: s1 MFMA  wave=(mtb,ntb); 2 imgs share B1; K=192 (6 chunks) ----
  f32x4 acc1[2][4];
  {
    half8 B1[6];
    #pragma unroll
    for (int u = 0; u < 6; ++u)
      B1[u] = *(const half8*)(w1e + (ntb*16 + row)*192 + u*32 + kg*8);
    #pragma unroll
    for (int im = 0; im < 2; ++im)
      #pragma unroll
      for (int t2 = 0; t2 < 4; ++t2) acc1[im][t2] = (f32x4){0,0,0,0};
    const int xoff = 8*(row + kg);
    #pragma unroll
    for (int t2 = 0; t2 < 4; ++t2) {
      const int py = mtb*4 + t2;
      #pragma unroll
      for (int u = 0; u < 6; ++u) {
        const int ro = (2*py + u)*160 + xoff;
        half8 a0 = *(const half8*)(Pimg + ro);
        half8 a1 = *(const half8*)(Pimg + 5760 + ro);
        acc1[0][t2] = __builtin_amdgcn_mfma_f32_16x16x32_f16(a0, B1[u], acc1[0][t2], 0, 0, 0);
        acc1[1][t2] = __builtin_amdgcn_mfma_f32_16x16x32_f16(a1, B1[u], acc1[1][t2], 0, 0, 0);
      }
    }
  }
  __syncthreads();                               // b2: Pimg dead

  // ---------- ph2: zero P2 borders + write s1 output (oc = 2*row + ntb) ----------
  for (int j = tid; j < 3200; j += 512) {        // 2 im x 400 pos x 4 half8
    int im = j / 1600, jj = j - im*1600;
    int u = jj & 3, pos = jj >> 2;
    int a = pos/20, c = pos - a*20;
    bool interior = ((unsigned)(a-2) < 16u) & ((unsigned)(c-2) < 16u);
    if (!interior) *(half8*)(P2 + im*16000 + pos*40 + u*8) = (half8)(_Float16)0.f;
  }
  {
    const int oc = 2*row + ntb;
    const float sA = bnc[oc], hA = bnc[32 + oc];
    #pragma unroll
    for (int im = 0; im < 2; ++im)
      #pragma unroll
      for (int t2 = 0; t2 < 4; ++t2) {
        const int py = mtb*4 + t2;
        #pragma unroll
        for (int r = 0; r < 4; ++r) {
          int px = kg*4 + r;
          P2[im*16000 + ((py+2)*20 + px+2)*40 + oc] =
              (_Float16)clamp01(fmaf(acc1[im][t2][r], sA, hA));
        }
      }
  }
  __syncthreads();                               // b3: P2 complete

  // ---------- ph3: s2 MFMA, 36 taps, one weight load -> 2 MFMAs, depth-4 prefetch ----
  f32x4 a2[2];
  a2[0] = (f32x4){0,0,0,0}; a2[1] = (f32x4){0,0,0,0};
  {
    const int pixel = mtb*16 + row;
    const int py = pixel >> 3, px = pixel & 7;
    const _Float16* base = P2 + (2*py)*800 + (2*px)*40 + kg*8;
    const _Float16* wb = w2e + (ntb*16 + row)*32 + kg*8;
    half8 wreg[4];
    #pragma unroll
    for (int q = 0; q < 4; ++q) wreg[q] = *(const half8*)(wb + q*1024);
    #pragma unroll
    for (int u = 0; u < 6; ++u)
      #pragma unroll
      for (int v = 0; v < 6; ++v) {
        const int tap = u*6 + v;
        const int tn = (tap < 32) ? tap + 4 : tap;
        half8 nw = *(const half8*)(wb + tn*1024);
        const int ro = u*800 + v*40;
        half8 av0 = *(const half8*)(base + ro);
        half8 av1 = *(const half8*)(base + 16000 + ro);
        a2[0] = __builtin_amdgcn_mfma_f32_16x16x32_f16(av0, wreg[tap & 3], a2[0], 0, 0, 0);
        a2[1] = __builtin_amdgcn_mfma_f32_16x16x32_f16(av1, wreg[tap & 3], a2[1], 0, 0, 0);
        wreg[tap & 3] = nw;
      }
  }
  __syncthreads();                               // b4: P2 reads done

  // ---------- ph4: zero P3 borders + write s2 output (oc = 2*row + ntb) ----------
  for (int j = tid; j < 1152; j += 512) {        // 2 im x 144 pos x 4 half8
    int im = j / 576, jj = j - im*576;
    int u = jj & 3, pos = jj >> 2;
    int a = pos/12, c = pos - a*12;
    bool interior = ((unsigned)(a-2) < 8u) & ((unsigned)(c-2) < 8u);
    if (!interior) *(half8*)(P3 + im*5760 + pos*40 + u*8) = (half8)(_Float16)0.f;
  }
  {
    const int oc = 2*row + ntb;
    const float sA = bnc[64 + oc], hA = bnc[96 + oc];
    #pragma unroll
    for (int im = 0; im < 2; ++im)
      #pragma unroll
      for (int r = 0; r < 4; ++r) {
        int p2 = mtb*16 + kg*4 + r;
        int py2 = p2 >> 3, px2 = p2 & 7;
        P3[im*5760 + ((py2+2)*12 + px2+2)*40 + oc] =
            (_Float16)clamp01(fmaf(a2[im][r], sA, hA));
      }
  }
  __syncthreads();                               // b5: P3 complete

  // ---------- ph5: s3 MFMA, ALL 8 waves: im = w>>2, nt = w&3 ----------
  {
    const int im = w >> 2, nt = w & 3;
    const int py = row >> 2, px = row & 3;
    const _Float16* base = P3 + im*5760 + (2*py)*480 + (2*px)*40 + kg*8;
    const _Float16* wb = w3e + (nt*16 + row)*32 + kg*8;
    half8 wreg[4];
    #pragma unroll
    for (int q = 0; q < 4; ++q) wreg[q] = *(const half8*)(wb + q*2048);
    f32x4 a3 = {0,0,0,0};
    #pragma unroll
    for (int u = 0; u < 6; ++u)
      #pragma unroll
      for (int v = 0; v < 6; ++v) {
        const int tap = u*6 + v;
        const int tn = (tap < 32) ? tap + 4 : tap;
        half8 nw = *(const half8*)(wb + tn*2048);
        half8 av = *(const half8*)(base + u*480 + v*40);
        a3 = __builtin_amdgcn_mfma_f32_16x16x32_f16(av, wreg[tap & 3], a3, 0, 0, 0);
        wreg[tap & 3] = nw;
      }
    const int oc = nt*16 + row;
    const float s3 = bnc[128 + oc], h3 = bnc[192 + oc];
    #pragma unroll
    for (int r = 0; r < 4; ++r)
      Ip3[im*1024 + (kg*4 + r)*64 + oc] = (_Float16)clamp01(fmaf(a3[r], s3, h3));
  }
  __syncthreads();                               // b6: Ip3 complete

  // ---------- ph6: fc 64x4x4 -> 10  + bn1d (VALU, f32 accum), 2 imgs ----------
  if (tid < 320) {
    const int im = tid / 160, t2 = tid - im*160;
    const int oc = t2 >> 4, pix = t2 & 15;
    const _Float16* A = Ip3 + im*1024 + pix*64;
    const _Float16* W = w4h + oc*1024 + pix*64;
    float a = 0.f;
    #pragma unroll
    for (int q = 0; q < 8; ++q) {
      half8 xa = *(const half8*)(A + q*8);
      half8 wv = *(const half8*)(W + q*8);
      #pragma unroll
      for (int j = 0; j < 8; ++j)
        a = fmaf((float)xa[j], (float)wv[j], a);
    }
    S4P[im*160 + t2] = a;
  }
  __syncthreads();                               // b7
  if (tid < 20) {
    const int im = tid / 10, oc = tid - im*10;
    float s = 0.f;
    #pragma unroll
    for (int i = 0; i < 16; ++i) s += S4P[im*160 + oc*16 + i];
    out[(i0+im)*10 + oc] = fmaf(s, bnc[256 + oc], bnc[266 + oc]);
  }
}

extern "C" void kernel_launch(void* const* d_in, const int* in_sizes, int n_in,
                              void* d_out, int out_size, void* d_ws, size_t ws_size,
                              hipStream_t stream)
{
  const float* x  = (const float*)d_in[0];
  const float* w1 = (const float*)d_in[1];
  const float* w2 = (const float*)d_in[2];
  const float* w3 = (const float*)d_in[3];
  const float* w4 = (const float*)d_in[4];
  const float *g1=(const float*)d_in[5],  *b1=(const float*)d_in[6],
              *m1=(const float*)d_in[7],  *v1=(const float*)d_in[8];
  const float *g2=(const float*)d_in[9],  *b2=(const float*)d_in[10],
              *m2=(const float*)d_in[11], *v2=(const float*)d_in[12];
  const float *g3=(const float*)d_in[13], *b3=(const float*)d_in[14],
              *m3=(const float*)d_in[15], *v3=(const float*)d_in[16];
  const float *g4=(const float*)d_in[17], *b4=(const float*)d_in[18],
              *m4=(const float*)d_in[19], *v4=(const float*)d_in[20];
  float* out = (float*)d_out;

  char* ws = (char*)d_ws;
  _Float16* w1e = (_Float16*)(ws);             //  12,288 B
  _Float16* w2e = (_Float16*)(ws + 12288);     //  73,728 B
  _Float16* w3e = (_Float16*)(ws + 86016);     // 147,456 B
  _Float16* w4h = (_Float16*)(ws + 233472);    //  32,768 B
  float*    bnc = (float*)   (ws + 266240);    //   1,152 B

  k_prep<<<dim3(128), dim3(256), 0, stream>>>(w1, w2, w3, w4,
      g1,b1,m1,v1, g2,b2,m2,v2, g3,b3,m3,v3, g4,b4,m4,v4,
      w1e, w2e, w3e, w4h, bnc);
  k_fused<<<dim3(512), dim3(512), 0, stream>>>(x, w1e, w2e, w3e, w4h, bnc, out);
}